// Round 1
// baseline (11935.908 us; speedup 1.0000x reference)
//
#include <hip/hip_runtime.h>

#define BATCH  4096
#define TIN    256
#define NIN    4
#define HDIM   64
#define TOUT   180
#define BB     16      // batch elements per block
#define NTHR   576     // 3 groups x 192 rows, 9 waves
#define HP     68      // padded stride for h arrays (kills head-phase bank conflicts)
#define G3     192     // 3*H gate rows

__device__ __forceinline__ float sigm(float v){ return 1.0f/(1.0f+__expf(-v)); }
__device__ __forceinline__ float tanh_(float v){ return 2.0f/(1.0f+__expf(-2.0f*v)) - 1.0f; }

__global__ __launch_bounds__(NTHR)
void gru_seq(const float* __restrict__ x,
             const float* __restrict__ eWih0, const float* __restrict__ eWhh0,
             const float* __restrict__ ebih0, const float* __restrict__ ebhh0,
             const float* __restrict__ eWih1, const float* __restrict__ eWhh1,
             const float* __restrict__ ebih1, const float* __restrict__ ebhh1,
             const float* __restrict__ dWih0, const float* __restrict__ dWhh0,
             const float* __restrict__ dbih0, const float* __restrict__ dbhh0,
             const float* __restrict__ dWih1, const float* __restrict__ dWhh1,
             const float* __restrict__ dbih1, const float* __restrict__ dbhh1,
             const float* __restrict__ Won,  const float* __restrict__ bon,
             const float* __restrict__ Wcv,  const float* __restrict__ bcv,
             float* __restrict__ out)
{
  __shared__ float h1[BB][HP];     // layer-0 hidden (encoder) == d1 (decoder)
  __shared__ float h2[BB][HP];     // layer-1 hidden == d2
  __shared__ float gi[BB][G3];     // input-side gates (reused L0 then L1)
  __shared__ float g0[BB][G3];     // hidden-side gates, layer 0
  __shared__ float g1[BB][G3];     // hidden-side gates, layer 1
  __shared__ float xb[2][BB][NIN]; // double-buffered x tile
  __shared__ float pv[BB];         // decoder feedback (cv)
  __shared__ float hw[2][HDIM];    // head weights (Won, Wcv)
  __shared__ float hbb[2];         // head biases

  const int tid = threadIdx.x;
  const int m   = tid / G3;        // 0: Whh0(+Wih0)  1: Wih1  2: Whh1
  const int j   = tid - m*G3;      // gate row 0..191
  const int bbase = blockIdx.x * BB;

  // ---- persistent per-thread weight row (16 float4 = 64 VGPRs) ----
  float4 w4[16];
  float4 wi0 = make_float4(0.f,0.f,0.f,0.f);
  float bi = 0.f, bh = 0.f;
  {
    const float* Wm = (m==0)? eWhh0 : (m==1)? eWih1 : eWhh1;
    const float4* Wr = (const float4*)(Wm + j*HDIM);
    #pragma unroll
    for (int kk=0;kk<16;kk++) w4[kk] = Wr[kk];
    if (m==0){ wi0 = *(const float4*)(eWih0 + j*NIN); bi = ebih0[j]; bh = ebhh0[j]; }
    else if (m==1){ bi = ebih1[j]; }
    else          { bh = ebhh1[j]; }
  }

  // init state + first x tile
  for (int u=tid; u<BB*HP; u+=NTHR){ (&h1[0][0])[u]=0.f; (&h2[0][0])[u]=0.f; }
  if (tid < BB)
    *(float4*)&xb[0][tid][0] = *(const float4*)(x + (size_t)(bbase+tid)*TIN*NIN);
  __syncthreads();

  // ================= encoder: 256 steps =================
  for (int t=0;t<TIN;t++){
    const int cur = t & 1;
    // Phase A: m0 -> gi0/gh0 from (x, h1); m2 -> gh1 from h2; m1 stages next x
    if (m==0){
      for (int b=0;b<BB;b++){
        float ai = bi + wi0.x*xb[cur][b][0] + wi0.y*xb[cur][b][1]
                      + wi0.z*xb[cur][b][2] + wi0.w*xb[cur][b][3];
        const float4* hv = (const float4*)&h1[b][0];
        float a0=0.f,a1=0.f,a2=0.f,a3=0.f;
        #pragma unroll
        for (int kk=0;kk<16;kk++){ float4 h4 = hv[kk];
          a0 += w4[kk].x*h4.x; a1 += w4[kk].y*h4.y;
          a2 += w4[kk].z*h4.z; a3 += w4[kk].w*h4.w; }
        gi[b][j] = ai;
        g0[b][j] = bh + ((a0+a1)+(a2+a3));
      }
    } else if (m==2){
      for (int b=0;b<BB;b++){
        const float4* hv = (const float4*)&h2[b][0];
        float a0=0.f,a1=0.f,a2=0.f,a3=0.f;
        #pragma unroll
        for (int kk=0;kk<16;kk++){ float4 h4 = hv[kk];
          a0 += w4[kk].x*h4.x; a1 += w4[kk].y*h4.y;
          a2 += w4[kk].z*h4.z; a3 += w4[kk].w*h4.w; }
        g1[b][j] = bh + ((a0+a1)+(a2+a3));
      }
    } else {
      const int l = tid - G3;
      if (l < BB && t+1 < TIN)
        *(float4*)&xb[cur^1][l][0] =
          *(const float4*)(x + ((size_t)(bbase+l)*TIN + (t+1))*NIN);
    }
    __syncthreads();
    // Phase B: combine layer 0 -> h1 (in place)
    for (int u=tid; u<BB*HDIM; u+=NTHR){
      const int b=u>>6, q=u&63;
      const float r = sigm(gi[b][q]      + g0[b][q]);
      const float z = sigm(gi[b][64+q]   + g0[b][64+q]);
      const float n = tanh_(gi[b][128+q] + r*g0[b][128+q]);
      h1[b][q] = (1.f-z)*n + z*h1[b][q];
    }
    __syncthreads();
    // Phase C: m1 -> gi1 = Wih1 @ h1_new
    if (m==1){
      for (int b=0;b<BB;b++){
        const float4* hv = (const float4*)&h1[b][0];
        float a0=0.f,a1=0.f,a2=0.f,a3=0.f;
        #pragma unroll
        for (int kk=0;kk<16;kk++){ float4 h4 = hv[kk];
          a0 += w4[kk].x*h4.x; a1 += w4[kk].y*h4.y;
          a2 += w4[kk].z*h4.z; a3 += w4[kk].w*h4.w; }
        gi[b][j] = bi + ((a0+a1)+(a2+a3));
      }
    }
    __syncthreads();
    // Phase D: combine layer 1 -> h2
    for (int u=tid; u<BB*HDIM; u+=NTHR){
      const int b=u>>6, q=u&63;
      const float r = sigm(gi[b][q]      + g1[b][q]);
      const float z = sigm(gi[b][64+q]   + g1[b][64+q]);
      const float n = tanh_(gi[b][128+q] + r*g1[b][128+q]);
      h2[b][q] = (1.f-z)*n + z*h2[b][q];
    }
    __syncthreads();
  }

  // ================= switch to decoder weights =================
  {
    const float* Wm = (m==0)? dWhh0 : (m==1)? dWih1 : dWhh1;
    const float4* Wr = (const float4*)(Wm + j*HDIM);
    #pragma unroll
    for (int kk=0;kk<16;kk++) w4[kk] = Wr[kk];
    if (m==0){ wi0.x = dWih0[j]; bi = dbih0[j]; bh = dbhh0[j]; }
    else if (m==1){ bi = dbih1[j]; }
    else          { bh = dbhh1[j]; }
  }
  if (tid < HDIM){ hw[0][tid] = Won[tid]; hw[1][tid] = Wcv[tid]; }
  if (tid == 0){ hbb[0] = bon[0]; hbb[1] = bcv[0]; }
  if (tid < BB) pv[tid] = 0.f;
  __syncthreads();

  // ================= decoder: 180 steps =================
  for (int s=0;s<TOUT;s++){
    if (m==0){
      for (int b=0;b<BB;b++){
        const float4* hv = (const float4*)&h1[b][0];
        float a0=0.f,a1=0.f,a2=0.f,a3=0.f;
        #pragma unroll
        for (int kk=0;kk<16;kk++){ float4 h4 = hv[kk];
          a0 += w4[kk].x*h4.x; a1 += w4[kk].y*h4.y;
          a2 += w4[kk].z*h4.z; a3 += w4[kk].w*h4.w; }
        gi[b][j] = bi + wi0.x*pv[b];
        g0[b][j] = bh + ((a0+a1)+(a2+a3));
      }
    } else if (m==2){
      for (int b=0;b<BB;b++){
        const float4* hv = (const float4*)&h2[b][0];
        float a0=0.f,a1=0.f,a2=0.f,a3=0.f;
        #pragma unroll
        for (int kk=0;kk<16;kk++){ float4 h4 = hv[kk];
          a0 += w4[kk].x*h4.x; a1 += w4[kk].y*h4.y;
          a2 += w4[kk].z*h4.z; a3 += w4[kk].w*h4.w; }
        g1[b][j] = bh + ((a0+a1)+(a2+a3));
      }
    }
    __syncthreads();
    for (int u=tid; u<BB*HDIM; u+=NTHR){
      const int b=u>>6, q=u&63;
      const float r = sigm(gi[b][q]      + g0[b][q]);
      const float z = sigm(gi[b][64+q]   + g0[b][64+q]);
      const float n = tanh_(gi[b][128+q] + r*g0[b][128+q]);
      h1[b][q] = (1.f-z)*n + z*h1[b][q];
    }
    __syncthreads();
    if (m==1){
      for (int b=0;b<BB;b++){
        const float4* hv = (const float4*)&h1[b][0];
        float a0=0.f,a1=0.f,a2=0.f,a3=0.f;
        #pragma unroll
        for (int kk=0;kk<16;kk++){ float4 h4 = hv[kk];
          a0 += w4[kk].x*h4.x; a1 += w4[kk].y*h4.y;
          a2 += w4[kk].z*h4.z; a3 += w4[kk].w*h4.w; }
        gi[b][j] = bi + ((a0+a1)+(a2+a3));
      }
    }
    __syncthreads();
    for (int u=tid; u<BB*HDIM; u+=NTHR){
      const int b=u>>6, q=u&63;
      const float r = sigm(gi[b][q]      + g1[b][q]);
      const float z = sigm(gi[b][64+q]   + g1[b][64+q]);
      const float n = tanh_(gi[b][128+q] + r*g1[b][128+q]);
      h2[b][q] = (1.f-z)*n + z*h2[b][q];
    }
    __syncthreads();
    // heads: logit & cv, feed cv back
    if (tid < 32){
      const int hd = tid>>4, b = tid&15;
      float a = hbb[hd];
      const float4* hv = (const float4*)&h2[b][0];
      #pragma unroll
      for (int kk=0;kk<16;kk++){ float4 h4 = hv[kk];
        a += hw[hd][kk*4+0]*h4.x + hw[hd][kk*4+1]*h4.y
           + hw[hd][kk*4+2]*h4.z + hw[hd][kk*4+3]*h4.w; }
      const int bg = bbase + b;
      if (hd==0) out[(size_t)bg*TOUT + s] = a;
      else { out[(size_t)BATCH*TOUT + (size_t)bg*TOUT + s] = a; pv[b] = a; }
    }
    __syncthreads();
  }
}

extern "C" void kernel_launch(void* const* d_in, const int* in_sizes, int n_in,
                              void* d_out, int out_size, void* d_ws, size_t ws_size,
                              hipStream_t stream)
{
  const float* x     = (const float*)d_in[0];
  const float* eWih0 = (const float*)d_in[1];
  const float* eWhh0 = (const float*)d_in[2];
  const float* ebih0 = (const float*)d_in[3];
  const float* ebhh0 = (const float*)d_in[4];
  const float* eWih1 = (const float*)d_in[5];
  const float* eWhh1 = (const float*)d_in[6];
  const float* ebih1 = (const float*)d_in[7];
  const float* ebhh1 = (const float*)d_in[8];
  const float* dWih0 = (const float*)d_in[9];
  const float* dWhh0 = (const float*)d_in[10];
  const float* dbih0 = (const float*)d_in[11];
  const float* dbhh0 = (const float*)d_in[12];
  const float* dWih1 = (const float*)d_in[13];
  const float* dWhh1 = (const float*)d_in[14];
  const float* dbih1 = (const float*)d_in[15];
  const float* dbhh1 = (const float*)d_in[16];
  const float* Won   = (const float*)d_in[17];
  const float* bon   = (const float*)d_in[18];
  const float* Wcv   = (const float*)d_in[19];
  const float* bcv   = (const float*)d_in[20];

  gru_seq<<<BATCH/BB, NTHR, 0, stream>>>(
      x, eWih0, eWhh0, ebih0, ebhh0, eWih1, eWhh1, ebih1, ebhh1,
      dWih0, dWhh0, dbih0, dbhh0, dWih1, dWhh1, dbih1, dbhh1,
      Won, bon, Wcv, bcv, (float*)d_out);
}

// Round 5
// 11931.601 us; speedup vs baseline: 1.0004x; 1.0004x over previous
//
#include <hip/hip_runtime.h>

#define BATCH  4096
#define TIN    256
#define NIN    4
#define HDIM   64
#define TOUT   180
#define BB     16      // batch elements per block
#define NTHR   576     // 3 groups x 192 rows, 9 waves
#define HP     68      // padded stride for h arrays (kills head-phase bank conflicts)
#define G3     192     // 3*H gate rows

__device__ __forceinline__ float sigm(float v){ return 1.0f/(1.0f+__expf(-v)); }
__device__ __forceinline__ float tanh_(float v){ return 2.0f/(1.0f+__expf(-2.0f*v)) - 1.0f; }

// (NTHR, 1): min 1 wave/EU -> VGPR cap ~170 (9 waves place 3/2/2/2 across the
// 4 SIMDs). Without this the allocator capped at 84 VGPRs and SPILLED the
// 64-VGPR persistent weight row to scratch: rocprof showed 20.7 GB FETCH_SIZE
// (inputs are 17 MB) and 12.2 ms. The weight rows MUST stay register-resident.
__global__ __launch_bounds__(NTHR, 1)
void gru_seq(const float* __restrict__ x,
             const float* __restrict__ eWih0, const float* __restrict__ eWhh0,
             const float* __restrict__ ebih0, const float* __restrict__ ebhh0,
             const float* __restrict__ eWih1, const float* __restrict__ eWhh1,
             const float* __restrict__ ebih1, const float* __restrict__ ebhh1,
             const float* __restrict__ dWih0, const float* __restrict__ dWhh0,
             const float* __restrict__ dbih0, const float* __restrict__ dbhh0,
             const float* __restrict__ dWih1, const float* __restrict__ dWhh1,
             const float* __restrict__ dbih1, const float* __restrict__ dbhh1,
             const float* __restrict__ Won,  const float* __restrict__ bon,
             const float* __restrict__ Wcv,  const float* __restrict__ bcv,
             float* __restrict__ out)
{
  __shared__ float h1[BB][HP];     // layer-0 hidden (encoder) == d1 (decoder)
  __shared__ float h2[BB][HP];     // layer-1 hidden == d2
  __shared__ float gi[BB][G3];     // input-side gates (reused L0 then L1)
  __shared__ float g0[BB][G3];     // hidden-side gates, layer 0
  __shared__ float g1[BB][G3];     // hidden-side gates, layer 1
  __shared__ float xb[2][BB][NIN]; // double-buffered x tile
  __shared__ float pv[BB];         // decoder feedback (cv)
  __shared__ float hw[2][HDIM];    // head weights (Won, Wcv)
  __shared__ float hbb[2];         // head biases

  const int tid = threadIdx.x;
  const int m   = tid / G3;        // 0: Whh0(+Wih0)  1: Wih1  2: Whh1
  const int j   = tid - m*G3;      // gate row 0..191
  const int bbase = blockIdx.x * BB;

  // ---- persistent per-thread weight row (16 float4 = 64 VGPRs) ----
  float4 w4[16];
  float4 wi0 = make_float4(0.f,0.f,0.f,0.f);
  float bi = 0.f, bh = 0.f;
  {
    const float* Wm = (m==0)? eWhh0 : (m==1)? eWih1 : eWhh1;
    const float4* Wr = (const float4*)(Wm + j*HDIM);
    #pragma unroll
    for (int kk=0;kk<16;kk++) w4[kk] = Wr[kk];
    if (m==0){ wi0 = *(const float4*)(eWih0 + j*NIN); bi = ebih0[j]; bh = ebhh0[j]; }
    else if (m==1){ bi = ebih1[j]; }
    else          { bh = ebhh1[j]; }
  }

  // init state + first x tile
  for (int u=tid; u<BB*HP; u+=NTHR){ (&h1[0][0])[u]=0.f; (&h2[0][0])[u]=0.f; }
  if (tid < BB)
    *(float4*)&xb[0][tid][0] = *(const float4*)(x + (size_t)(bbase+tid)*TIN*NIN);
  __syncthreads();

  // ================= encoder: 256 steps =================
  for (int t=0;t<TIN;t++){
    const int cur = t & 1;
    // Phase A: m0 -> gi0/gh0 from (x, h1); m2 -> gh1 from h2; m1 stages next x
    if (m==0){
      for (int b=0;b<BB;b++){
        float ai = bi + wi0.x*xb[cur][b][0] + wi0.y*xb[cur][b][1]
                      + wi0.z*xb[cur][b][2] + wi0.w*xb[cur][b][3];
        const float4* hv = (const float4*)&h1[b][0];
        float a0=0.f,a1=0.f,a2=0.f,a3=0.f;
        #pragma unroll
        for (int kk=0;kk<16;kk++){ float4 h4 = hv[kk];
          a0 += w4[kk].x*h4.x; a1 += w4[kk].y*h4.y;
          a2 += w4[kk].z*h4.z; a3 += w4[kk].w*h4.w; }
        gi[b][j] = ai;
        g0[b][j] = bh + ((a0+a1)+(a2+a3));
      }
    } else if (m==2){
      for (int b=0;b<BB;b++){
        const float4* hv = (const float4*)&h2[b][0];
        float a0=0.f,a1=0.f,a2=0.f,a3=0.f;
        #pragma unroll
        for (int kk=0;kk<16;kk++){ float4 h4 = hv[kk];
          a0 += w4[kk].x*h4.x; a1 += w4[kk].y*h4.y;
          a2 += w4[kk].z*h4.z; a3 += w4[kk].w*h4.w; }
        g1[b][j] = bh + ((a0+a1)+(a2+a3));
      }
    } else {
      const int l = tid - G3;
      if (l < BB && t+1 < TIN)
        *(float4*)&xb[cur^1][l][0] =
          *(const float4*)(x + ((size_t)(bbase+l)*TIN + (t+1))*NIN);
    }
    __syncthreads();
    // Phase B: combine layer 0 -> h1 (in place)
    for (int u=tid; u<BB*HDIM; u+=NTHR){
      const int b=u>>6, q=u&63;
      const float r = sigm(gi[b][q]      + g0[b][q]);
      const float z = sigm(gi[b][64+q]   + g0[b][64+q]);
      const float n = tanh_(gi[b][128+q] + r*g0[b][128+q]);
      h1[b][q] = (1.f-z)*n + z*h1[b][q];
    }
    __syncthreads();
    // Phase C: m1 -> gi1 = Wih1 @ h1_new
    if (m==1){
      for (int b=0;b<BB;b++){
        const float4* hv = (const float4*)&h1[b][0];
        float a0=0.f,a1=0.f,a2=0.f,a3=0.f;
        #pragma unroll
        for (int kk=0;kk<16;kk++){ float4 h4 = hv[kk];
          a0 += w4[kk].x*h4.x; a1 += w4[kk].y*h4.y;
          a2 += w4[kk].z*h4.z; a3 += w4[kk].w*h4.w; }
        gi[b][j] = bi + ((a0+a1)+(a2+a3));
      }
    }
    __syncthreads();
    // Phase D: combine layer 1 -> h2
    for (int u=tid; u<BB*HDIM; u+=NTHR){
      const int b=u>>6, q=u&63;
      const float r = sigm(gi[b][q]      + g1[b][q]);
      const float z = sigm(gi[b][64+q]   + g1[b][64+q]);
      const float n = tanh_(gi[b][128+q] + r*g1[b][128+q]);
      h2[b][q] = (1.f-z)*n + z*h2[b][q];
    }
    __syncthreads();
  }

  // ================= switch to decoder weights =================
  {
    const float* Wm = (m==0)? dWhh0 : (m==1)? dWih1 : dWhh1;
    const float4* Wr = (const float4*)(Wm + j*HDIM);
    #pragma unroll
    for (int kk=0;kk<16;kk++) w4[kk] = Wr[kk];
    if (m==0){ wi0.x = dWih0[j]; bi = dbih0[j]; bh = dbhh0[j]; }
    else if (m==1){ bi = dbih1[j]; }
    else          { bh = dbhh1[j]; }
  }
  if (tid < HDIM){ hw[0][tid] = Won[tid]; hw[1][tid] = Wcv[tid]; }
  if (tid == 0){ hbb[0] = bon[0]; hbb[1] = bcv[0]; }
  if (tid < BB) pv[tid] = 0.f;
  __syncthreads();

  // ================= decoder: 180 steps =================
  for (int s=0;s<TOUT;s++){
    if (m==0){
      for (int b=0;b<BB;b++){
        const float4* hv = (const float4*)&h1[b][0];
        float a0=0.f,a1=0.f,a2=0.f,a3=0.f;
        #pragma unroll
        for (int kk=0;kk<16;kk++){ float4 h4 = hv[kk];
          a0 += w4[kk].x*h4.x; a1 += w4[kk].y*h4.y;
          a2 += w4[kk].z*h4.z; a3 += w4[kk].w*h4.w; }
        gi[b][j] = bi + wi0.x*pv[b];
        g0[b][j] = bh + ((a0+a1)+(a2+a3));
      }
    } else if (m==2){
      for (int b=0;b<BB;b++){
        const float4* hv = (const float4*)&h2[b][0];
        float a0=0.f,a1=0.f,a2=0.f,a3=0.f;
        #pragma unroll
        for (int kk=0;kk<16;kk++){ float4 h4 = hv[kk];
          a0 += w4[kk].x*h4.x; a1 += w4[kk].y*h4.y;
          a2 += w4[kk].z*h4.z; a3 += w4[kk].w*h4.w; }
        g1[b][j] = bh + ((a0+a1)+(a2+a3));
      }
    }
    __syncthreads();
    for (int u=tid; u<BB*HDIM; u+=NTHR){
      const int b=u>>6, q=u&63;
      const float r = sigm(gi[b][q]      + g0[b][q]);
      const float z = sigm(gi[b][64+q]   + g0[b][64+q]);
      const float n = tanh_(gi[b][128+q] + r*g0[b][128+q]);
      h1[b][q] = (1.f-z)*n + z*h1[b][q];
    }
    __syncthreads();
    if (m==1){
      for (int b=0;b<BB;b++){
        const float4* hv = (const float4*)&h1[b][0];
        float a0=0.f,a1=0.f,a2=0.f,a3=0.f;
        #pragma unroll
        for (int kk=0;kk<16;kk++){ float4 h4 = hv[kk];
          a0 += w4[kk].x*h4.x; a1 += w4[kk].y*h4.y;
          a2 += w4[kk].z*h4.z; a3 += w4[kk].w*h4.w; }
        gi[b][j] = bi + ((a0+a1)+(a2+a3));
      }
    }
    __syncthreads();
    for (int u=tid; u<BB*HDIM; u+=NTHR){
      const int b=u>>6, q=u&63;
      const float r = sigm(gi[b][q]      + g1[b][q]);
      const float z = sigm(gi[b][64+q]   + g1[b][64+q]);
      const float n = tanh_(gi[b][128+q] + r*g1[b][128+q]);
      h2[b][q] = (1.f-z)*n + z*h2[b][q];
    }
    __syncthreads();
    // heads: logit & cv, feed cv back
    if (tid < 32){
      const int hd = tid>>4, b = tid&15;
      float a = hbb[hd];
      const float4* hv = (const float4*)&h2[b][0];
      #pragma unroll
      for (int kk=0;kk<16;kk++){ float4 h4 = hv[kk];
        a += hw[hd][kk*4+0]*h4.x + hw[hd][kk*4+1]*h4.y
           + hw[hd][kk*4+2]*h4.z + hw[hd][kk*4+3]*h4.w; }
      const int bg = bbase + b;
      if (hd==0) out[(size_t)bg*TOUT + s] = a;
      else { out[(size_t)BATCH*TOUT + (size_t)bg*TOUT + s] = a; pv[b] = a; }
    }
    __syncthreads();
  }
}

extern "C" void kernel_launch(void* const* d_in, const int* in_sizes, int n_in,
                              void* d_out, int out_size, void* d_ws, size_t ws_size,
                              hipStream_t stream)
{
  const float* x     = (const float*)d_in[0];
  const float* eWih0 = (const float*)d_in[1];
  const float* eWhh0 = (const float*)d_in[2];
  const float* ebih0 = (const float*)d_in[3];
  const float* ebhh0 = (const float*)d_in[4];
  const float* eWih1 = (const float*)d_in[5];
  const float* eWhh1 = (const float*)d_in[6];
  const float* ebih1 = (const float*)d_in[7];
  const float* ebhh1 = (const float*)d_in[8];
  const float* dWih0 = (const float*)d_in[9];
  const float* dWhh0 = (const float*)d_in[10];
  const float* dbih0 = (const float*)d_in[11];
  const float* dbhh0 = (const float*)d_in[12];
  const float* dWih1 = (const float*)d_in[13];
  const float* dWhh1 = (const float*)d_in[14];
  const float* dbih1 = (const float*)d_in[15];
  const float* dbhh1 = (const float*)d_in[16];
  const float* Won   = (const float*)d_in[17];
  const float* bon   = (const float*)d_in[18];
  const float* Wcv   = (const float*)d_in[19];
  const float* bcv   = (const float*)d_in[20];

  gru_seq<<<BATCH/BB, NTHR, 0, stream>>>(
      x, eWih0, eWhh0, ebih0, ebhh0, eWih1, eWhh1, ebih1, ebhh1,
      dWih0, dWhh0, dbih0, dbhh0, dWih1, dWhh1, dbih1, dbhh1,
      Won, bon, Wcv, bcv, (float*)d_out);
}

// Round 6
// 7923.595 us; speedup vs baseline: 1.5064x; 1.5058x over previous
//
#include <hip/hip_runtime.h>

#define BATCH  4096
#define TIN    256
#define NIN    4
#define HDIM   64
#define TOUT   180
#define BB     16      // batch elements per block
#define NTHR   576     // 3 groups x 192 rows, 9 waves
#define HP     68      // padded stride for h arrays (kills head-phase bank conflicts)
#define G3     192     // 3*H gate rows
#define PADF   4096    // 16 KB LDS pad -> total ~63 KB (see comment below)

__device__ __forceinline__ float sigm(float v){ return 1.0f/(1.0f+__expf(-v)); }
__device__ __forceinline__ float tanh_(float v){ return 2.0f/(1.0f+__expf(-2.0f*v)) - 1.0f; }

// WHY THE PAD + ATTRIBUTE: the backend sets the VGPR budget from the
// LDS-limited occupancy: at 47 KB LDS -> 3 blocks/CU * 9 waves = 6 waves/EU
// -> budget 512/6 = 84 VGPRs (measured: VGPR_Count=84 in r1 AND r5 - the
// launch_bounds 2nd arg is only a MIN bound and did nothing). 84 cannot hold
// the 64-VGPR persistent weight row across phase barriers -> live-range
// split to scratch -> 20.7 GB HBM/dispatch (matches 184KB/block/step model).
// Padding LDS to ~63 KB -> 2 blocks/CU occupancy target -> budget 128.
// amdgpu_waves_per_eu(1,2) additionally requests a <=2-wave target (cap then
// comes from 9-wave-block launchability: <=170). Grid=256 = 1 block/CU
// regardless, so the pad costs nothing at runtime.
__global__ __launch_bounds__(NTHR)
__attribute__((amdgpu_waves_per_eu(1, 2)))
void gru_seq(const float* __restrict__ x,
             const float* __restrict__ eWih0, const float* __restrict__ eWhh0,
             const float* __restrict__ ebih0, const float* __restrict__ ebhh0,
             const float* __restrict__ eWih1, const float* __restrict__ eWhh1,
             const float* __restrict__ ebih1, const float* __restrict__ ebhh1,
             const float* __restrict__ dWih0, const float* __restrict__ dWhh0,
             const float* __restrict__ dbih0, const float* __restrict__ dbhh0,
             const float* __restrict__ dWih1, const float* __restrict__ dWhh1,
             const float* __restrict__ dbih1, const float* __restrict__ dbhh1,
             const float* __restrict__ Won,  const float* __restrict__ bon,
             const float* __restrict__ Wcv,  const float* __restrict__ bcv,
             float* __restrict__ out)
{
  __shared__ float h1[BB][HP];     // layer-0 hidden (encoder) == d1 (decoder)
  __shared__ float h2[BB][HP];     // layer-1 hidden == d2
  __shared__ float gi[BB][G3];     // input-side gates (reused L0 then L1)
  __shared__ float g0[BB][G3];     // hidden-side gates, layer 0
  __shared__ float g1[BB][G3];     // hidden-side gates, layer 1
  __shared__ float xb[2][BB][NIN]; // double-buffered x tile
  __shared__ float pv[BB];         // decoder feedback (cv)
  __shared__ float hw[2][HDIM];    // head weights (Won, Wcv)
  __shared__ float hbb[2];         // head biases
  __shared__ float lds_pad[PADF];  // occupancy-target pad (see header comment)

  const int tid = threadIdx.x;
  const int m   = tid / G3;        // 0: Whh0(+Wih0)  1: Wih1  2: Whh1
  const int j   = tid - m*G3;      // gate row 0..191
  const int bbase = blockIdx.x * BB;

  // volatile store so the pad array cannot be elided; negligible cost
  { volatile float* vp = lds_pad; vp[tid] = 0.f; }

  // ---- persistent per-thread weight row (16 float4 = 64 VGPRs) ----
  float4 w4[16];
  float4 wi0 = make_float4(0.f,0.f,0.f,0.f);
  float bi = 0.f, bh = 0.f;
  {
    const float* Wm = (m==0)? eWhh0 : (m==1)? eWih1 : eWhh1;
    const float4* Wr = (const float4*)(Wm + j*HDIM);
    #pragma unroll
    for (int kk=0;kk<16;kk++) w4[kk] = Wr[kk];
    if (m==0){ wi0 = *(const float4*)(eWih0 + j*NIN); bi = ebih0[j]; bh = ebhh0[j]; }
    else if (m==1){ bi = ebih1[j]; }
    else          { bh = ebhh1[j]; }
  }

  // init state + first x tile
  for (int u=tid; u<BB*HP; u+=NTHR){ (&h1[0][0])[u]=0.f; (&h2[0][0])[u]=0.f; }
  if (tid < BB)
    *(float4*)&xb[0][tid][0] = *(const float4*)(x + (size_t)(bbase+tid)*TIN*NIN);
  __syncthreads();

  // ================= encoder: 256 steps =================
  for (int t=0;t<TIN;t++){
    const int cur = t & 1;
    // Phase A: m0 -> gi0/gh0 from (x, h1); m2 -> gh1 from h2; m1 stages next x
    if (m==0){
      for (int b=0;b<BB;b++){
        float ai = bi + wi0.x*xb[cur][b][0] + wi0.y*xb[cur][b][1]
                      + wi0.z*xb[cur][b][2] + wi0.w*xb[cur][b][3];
        const float4* hv = (const float4*)&h1[b][0];
        float a0=0.f,a1=0.f,a2=0.f,a3=0.f;
        #pragma unroll
        for (int kk=0;kk<16;kk++){ float4 h4 = hv[kk];
          a0 += w4[kk].x*h4.x; a1 += w4[kk].y*h4.y;
          a2 += w4[kk].z*h4.z; a3 += w4[kk].w*h4.w; }
        gi[b][j] = ai;
        g0[b][j] = bh + ((a0+a1)+(a2+a3));
      }
    } else if (m==2){
      for (int b=0;b<BB;b++){
        const float4* hv = (const float4*)&h2[b][0];
        float a0=0.f,a1=0.f,a2=0.f,a3=0.f;
        #pragma unroll
        for (int kk=0;kk<16;kk++){ float4 h4 = hv[kk];
          a0 += w4[kk].x*h4.x; a1 += w4[kk].y*h4.y;
          a2 += w4[kk].z*h4.z; a3 += w4[kk].w*h4.w; }
        g1[b][j] = bh + ((a0+a1)+(a2+a3));
      }
    } else {
      const int l = tid - G3;
      if (l < BB && t+1 < TIN)
        *(float4*)&xb[cur^1][l][0] =
          *(const float4*)(x + ((size_t)(bbase+l)*TIN + (t+1))*NIN);
    }
    __syncthreads();
    // Phase B: combine layer 0 -> h1 (in place)
    for (int u=tid; u<BB*HDIM; u+=NTHR){
      const int b=u>>6, q=u&63;
      const float r = sigm(gi[b][q]      + g0[b][q]);
      const float z = sigm(gi[b][64+q]   + g0[b][64+q]);
      const float n = tanh_(gi[b][128+q] + r*g0[b][128+q]);
      h1[b][q] = (1.f-z)*n + z*h1[b][q];
    }
    __syncthreads();
    // Phase C: m1 -> gi1 = Wih1 @ h1_new
    if (m==1){
      for (int b=0;b<BB;b++){
        const float4* hv = (const float4*)&h1[b][0];
        float a0=0.f,a1=0.f,a2=0.f,a3=0.f;
        #pragma unroll
        for (int kk=0;kk<16;kk++){ float4 h4 = hv[kk];
          a0 += w4[kk].x*h4.x; a1 += w4[kk].y*h4.y;
          a2 += w4[kk].z*h4.z; a3 += w4[kk].w*h4.w; }
        gi[b][j] = bi + ((a0+a1)+(a2+a3));
      }
    }
    __syncthreads();
    // Phase D: combine layer 1 -> h2
    for (int u=tid; u<BB*HDIM; u+=NTHR){
      const int b=u>>6, q=u&63;
      const float r = sigm(gi[b][q]      + g1[b][q]);
      const float z = sigm(gi[b][64+q]   + g1[b][64+q]);
      const float n = tanh_(gi[b][128+q] + r*g1[b][128+q]);
      h2[b][q] = (1.f-z)*n + z*h2[b][q];
    }
    __syncthreads();
  }

  // ================= switch to decoder weights =================
  {
    const float* Wm = (m==0)? dWhh0 : (m==1)? dWih1 : dWhh1;
    const float4* Wr = (const float4*)(Wm + j*HDIM);
    #pragma unroll
    for (int kk=0;kk<16;kk++) w4[kk] = Wr[kk];
    if (m==0){ wi0.x = dWih0[j]; bi = dbih0[j]; bh = dbhh0[j]; }
    else if (m==1){ bi = dbih1[j]; }
    else          { bh = dbhh1[j]; }
  }
  if (tid < HDIM){ hw[0][tid] = Won[tid]; hw[1][tid] = Wcv[tid]; }
  if (tid == 0){ hbb[0] = bon[0]; hbb[1] = bcv[0]; }
  if (tid < BB) pv[tid] = 0.f;
  __syncthreads();

  // ================= decoder: 180 steps =================
  for (int s=0;s<TOUT;s++){
    if (m==0){
      for (int b=0;b<BB;b++){
        const float4* hv = (const float4*)&h1[b][0];
        float a0=0.f,a1=0.f,a2=0.f,a3=0.f;
        #pragma unroll
        for (int kk=0;kk<16;kk++){ float4 h4 = hv[kk];
          a0 += w4[kk].x*h4.x; a1 += w4[kk].y*h4.y;
          a2 += w4[kk].z*h4.z; a3 += w4[kk].w*h4.w; }
        gi[b][j] = bi + wi0.x*pv[b];
        g0[b][j] = bh + ((a0+a1)+(a2+a3));
      }
    } else if (m==2){
      for (int b=0;b<BB;b++){
        const float4* hv = (const float4*)&h2[b][0];
        float a0=0.f,a1=0.f,a2=0.f,a3=0.f;
        #pragma unroll
        for (int kk=0;kk<16;kk++){ float4 h4 = hv[kk];
          a0 += w4[kk].x*h4.x; a1 += w4[kk].y*h4.y;
          a2 += w4[kk].z*h4.z; a3 += w4[kk].w*h4.w; }
        g1[b][j] = bh + ((a0+a1)+(a2+a3));
      }
    }
    __syncthreads();
    for (int u=tid; u<BB*HDIM; u+=NTHR){
      const int b=u>>6, q=u&63;
      const float r = sigm(gi[b][q]      + g0[b][q]);
      const float z = sigm(gi[b][64+q]   + g0[b][64+q]);
      const float n = tanh_(gi[b][128+q] + r*g0[b][128+q]);
      h1[b][q] = (1.f-z)*n + z*h1[b][q];
    }
    __syncthreads();
    if (m==1){
      for (int b=0;b<BB;b++){
        const float4* hv = (const float4*)&h1[b][0];
        float a0=0.f,a1=0.f,a2=0.f,a3=0.f;
        #pragma unroll
        for (int kk=0;kk<16;kk++){ float4 h4 = hv[kk];
          a0 += w4[kk].x*h4.x; a1 += w4[kk].y*h4.y;
          a2 += w4[kk].z*h4.z; a3 += w4[kk].w*h4.w; }
        gi[b][j] = bi + ((a0+a1)+(a2+a3));
      }
    }
    __syncthreads();
    for (int u=tid; u<BB*HDIM; u+=NTHR){
      const int b=u>>6, q=u&63;
      const float r = sigm(gi[b][q]      + g1[b][q]);
      const float z = sigm(gi[b][64+q]   + g1[b][64+q]);
      const float n = tanh_(gi[b][128+q] + r*g1[b][128+q]);
      h2[b][q] = (1.f-z)*n + z*h2[b][q];
    }
    __syncthreads();
    // heads: logit & cv, feed cv back
    if (tid < 32){
      const int hd = tid>>4, b = tid&15;
      float a = hbb[hd];
      const float4* hv = (const float4*)&h2[b][0];
      #pragma unroll
      for (int kk=0;kk<16;kk++){ float4 h4 = hv[kk];
        a += hw[hd][kk*4+0]*h4.x + hw[hd][kk*4+1]*h4.y
           + hw[hd][kk*4+2]*h4.z + hw[hd][kk*4+3]*h4.w; }
      const int bg = bbase + b;
      if (hd==0) out[(size_t)bg*TOUT + s] = a;
      else { out[(size_t)BATCH*TOUT + (size_t)bg*TOUT + s] = a; pv[b] = a; }
    }
    __syncthreads();
  }
}

extern "C" void kernel_launch(void* const* d_in, const int* in_sizes, int n_in,
                              void* d_out, int out_size, void* d_ws, size_t ws_size,
                              hipStream_t stream)
{
  const float* x     = (const float*)d_in[0];
  const float* eWih0 = (const float*)d_in[1];
  const float* eWhh0 = (const float*)d_in[2];
  const float* ebih0 = (const float*)d_in[3];
  const float* ebhh0 = (const float*)d_in[4];
  const float* eWih1 = (const float*)d_in[5];
  const float* eWhh1 = (const float*)d_in[6];
  const float* ebih1 = (const float*)d_in[7];
  const float* ebhh1 = (const float*)d_in[8];
  const float* dWih0 = (const float*)d_in[9];
  const float* dWhh0 = (const float*)d_in[10];
  const float* dbih0 = (const float*)d_in[11];
  const float* dbhh0 = (const float*)d_in[12];
  const float* dWih1 = (const float*)d_in[13];
  const float* dWhh1 = (const float*)d_in[14];
  const float* dbih1 = (const float*)d_in[15];
  const float* dbhh1 = (const float*)d_in[16];
  const float* Won   = (const float*)d_in[17];
  const float* bon   = (const float*)d_in[18];
  const float* Wcv   = (const float*)d_in[19];
  const float* bcv   = (const float*)d_in[20];

  gru_seq<<<BATCH/BB, NTHR, 0, stream>>>(
      x, eWih0, eWhh0, ebih0, ebhh0, eWih1, eWhh1, ebih1, ebhh1,
      dWih0, dWhh0, dbih0, dbhh0, dWih1, dWhh1, dbih1, dbhh1,
      Won, bon, Wcv, bcv, (float*)d_out);
}